// Round 8
// baseline (519.723 us; speedup 1.0000x reference)
//
#include <hip/hip_runtime.h>
#include <hip/hip_bf16.h>

#define NN 50000
#define EE 800000
#define IND 64
#define HD 128

typedef __hip_bfloat16 bf16;
typedef _Float16 fp16;
typedef _Float16 half8 __attribute__((ext_vector_type(8)));

__device__ __forceinline__ float loadT(const void* p, size_t i, int f32) {
    if (f32) return ((const float*)p)[i];
    return __bfloat162float(((const bf16*)p)[i]);
}

__device__ __forceinline__ int xcc_id() {
    int x;
    asm volatile("s_getreg_b32 %0, hwreg(HW_REG_XCC_ID)" : "=s"(x));
    return x & 7;
}

// flag=1 if float inputs are fp32, flag=0 if bf16.
__global__ void detect_kernel(const unsigned short* __restrict__ xraw,
                              int* __restrict__ flag) {
    if (threadIdx.x == 0) {
        int f = 0;
        for (int i = 0; i < 256; i += 2) {
            unsigned int w = ((unsigned int)xraw[i]) << 16;
            float a = fabsf(__uint_as_float(w));
            if (!(a <= 1.0e6f)) f = 1;
        }
        *flag = f;
    }
}

__global__ void fill_sentinel(bf16* __restrict__ out, int n) {
    int i = blockIdx.x * 256 + threadIdx.x;
    if (i < n) out[i] = __float2bfloat16(0.123f);
}

// Per-XCD histograms via workgroup-scope atomics (stay in the XCD's own L2;
// copy index = runtime XCD id -> coherent within each copy).
__global__ __launch_bounds__(256) void degree_kernel(const int* __restrict__ src,
                                                     const int* __restrict__ dst,
                                                     int* __restrict__ histo8) {
    int x = xcc_id();
    int* hs = histo8 + (size_t)x * 2 * NN;
    int* hd = hs + NN;
    int t = blockIdx.x * 1024 + threadIdx.x;
#pragma unroll
    for (int k = 0; k < 4; ++k) {
        int e = t + k * 256;
        if (e < EE) {
            int s = src[e];
            int d = dst[e];
            __hip_atomic_fetch_add(&hs[s], 1, __ATOMIC_RELAXED, __HIP_MEMORY_SCOPE_WORKGROUP);
            __hip_atomic_fetch_add(&hd[d], 1, __ATOMIC_RELAXED, __HIP_MEMORY_SCOPE_WORKGROUP);
        }
    }
}

// Sum 8 per-XCD histograms -> norms; block-level scan of deg_in.
__global__ __launch_bounds__(256) void norm_scan_kernel(const int* __restrict__ histo8,
                                                        float* __restrict__ norm_src,
                                                        float* __restrict__ norm_dst,
                                                        int* __restrict__ row_ofs,
                                                        int* __restrict__ bsum) {
    __shared__ int sm[256];
    int t = threadIdx.x;
    int i = blockIdx.x * 256 + t;
    int s = 0, d = 0;
    if (i < NN) {
#pragma unroll
        for (int x = 0; x < 8; ++x) {
            s += histo8[(size_t)x * 2 * NN + i];
            d += histo8[(size_t)x * 2 * NN + NN + i];
        }
        norm_src[i] = rsqrtf((float)(s < 1 ? 1 : s));
        norm_dst[i] = rsqrtf((float)(d < 1 ? 1 : d));
    }
    sm[t] = d;
    __syncthreads();
    for (int ofs = 1; ofs < 256; ofs <<= 1) {
        int add = (t >= ofs) ? sm[t - ofs] : 0;
        __syncthreads();
        sm[t] += add;
        __syncthreads();
    }
    if (i < NN) row_ofs[i] = sm[t] - d;
    if (t == 255) bsum[blockIdx.x] = sm[255];
}

__global__ __launch_bounds__(256) void scan2_kernel(int* __restrict__ bsum, int nb) {
    __shared__ int s[256];
    int t = threadIdx.x;
    int v = (t < nb) ? bsum[t] : 0;
    s[t] = v;
    __syncthreads();
    for (int ofs = 1; ofs < 256; ofs <<= 1) {
        int add = (t >= ofs) ? s[t - ofs] : 0;
        __syncthreads();
        s[t] += add;
        __syncthreads();
    }
    if (t < nb) bsum[t] = s[t] - v;
}

__global__ __launch_bounds__(256) void scan3_kernel(int* __restrict__ row_ofs,
                                                    int* __restrict__ cur,
                                                    const int* __restrict__ bsum) {
    int t = threadIdx.x;
    int i = blockIdx.x * 256 + t;
    if (i < NN) {
        int v = row_ofs[i] + bsum[blockIdx.x];
        row_ofs[i] = v;
        cur[i] = v;
    }
    if (i == 0) row_ofs[NN] = EE;
}

// CSR bucket fill: device-scope cursors (global uniqueness required); 8-deep ILP.
__global__ __launch_bounds__(256) void fill_kernel(const int* __restrict__ src,
                                                   const int* __restrict__ dst,
                                                   int* __restrict__ cur,
                                                   int* __restrict__ csr_src) {
    int t = blockIdx.x * 2048 + threadIdx.x;
    int sv[8], pv[8];
#pragma unroll
    for (int k = 0; k < 8; ++k) {
        int e = t + k * 256;
        pv[k] = -1;
        sv[k] = 0;
        if (e < EE) { sv[k] = src[e]; pv[k] = atomicAdd(&cur[dst[e]], 1); }
    }
#pragma unroll
    for (int k = 0; k < 8; ++k)
        if (pv[k] >= 0) csr_src[pv[k]] = sv[k];
}

// h[row,j] = fp16( relu(x @ Wp + bp) ); 16 rows/block (norm_src NOT folded here;
// it is applied in pgemm's epilogue per the associativity restructure).
__global__ __launch_bounds__(256) void proj_kernel(const void* __restrict__ x,
                                                   const void* __restrict__ Wp,
                                                   const void* __restrict__ bp,
                                                   fp16* __restrict__ h,
                                                   const int* __restrict__ flag) {
    int f32 = *flag;
    __shared__ float xs[16 * IND];
    int row0 = blockIdx.x * 16;
    for (int i = threadIdx.x; i < 16 * IND; i += 256) {
        int r = i >> 6, c = i & 63;
        xs[i] = loadT(x, (size_t)(row0 + r) * IND + c, f32);
    }
    __syncthreads();
    int j = threadIdx.x & 127;
    int rr = threadIdx.x >> 7;
    float acc[8] = {0.f, 0.f, 0.f, 0.f, 0.f, 0.f, 0.f, 0.f};
    for (int k = 0; k < IND; ++k) {
        float w = loadT(Wp, (size_t)k * HD + j, f32);
#pragma unroll
        for (int r = 0; r < 8; ++r) acc[r] += xs[(rr * 8 + r) * IND + k] * w;
    }
    float b = loadT(bp, j, f32);
#pragma unroll
    for (int r = 0; r < 8; ++r) {
        int row = row0 + rr * 8 + r;
        h[(size_t)row * HD + j] = (fp16)fmaxf(acc[r] + b, 0.0f);
    }
}

// p[row,:] = norm_src[row] * (h[row,:] @ W);  16 rows/block, VALU, LDS-staged h.
// (norm_src ⊙ h) @ W == norm_src ⊙ (h @ W): per-row scale commutes with @W.
__global__ __launch_bounds__(256) void pgemm_kernel(const fp16* __restrict__ h,
                                                    const void* __restrict__ W,
                                                    int wofs,
                                                    const float* __restrict__ norm_src,
                                                    const int* __restrict__ flag,
                                                    fp16* __restrict__ p) {
    int f32 = *flag;
    __shared__ float as[16 * HD];
    int row0 = blockIdx.x * 16;
    for (int i = threadIdx.x; i < 16 * HD; i += 256) {
        int r = i >> 7;
        as[i] = (float)h[(size_t)(row0 + r) * HD + (i & 127)];
    }
    __syncthreads();
    int j = threadIdx.x & 127;
    int rr = threadIdx.x >> 7;
    float acc[8] = {0.f, 0.f, 0.f, 0.f, 0.f, 0.f, 0.f, 0.f};
    for (int k = 0; k < HD; ++k) {
        float w = loadT(W, (size_t)wofs + (size_t)k * HD + j, f32);
#pragma unroll
        for (int r = 0; r < 8; ++r) acc[r] += as[(rr * 8 + r) * HD + k] * w;
    }
#pragma unroll
    for (int r = 0; r < 8; ++r) {
        int row = row0 + rr * 8 + r;
        p[(size_t)row * HD + j] = (fp16)(acc[r] * norm_src[row]);
    }
}

// Pure gather: out[n,:] = relu(norm_dst[n] * sum_e p[csr_src[e],:] + bias).
// 16 nodes/block, 16 lanes/node (16 B fp16x8), 4 edges in flight.
__global__ __launch_bounds__(256) void gather_kernel(const fp16* __restrict__ p,
                                                     const int* __restrict__ row_ofs,
                                                     const int* __restrict__ csr_src,
                                                     const float* __restrict__ norm_dst,
                                                     const void* __restrict__ bias,
                                                     int bofs,
                                                     const int* __restrict__ flag,
                                                     fp16* __restrict__ h_out,
                                                     void* __restrict__ outv,
                                                     int is_final) {
    int f32 = *flag;
    int g = threadIdx.x >> 4;
    int c = threadIdx.x & 15;
    int n = blockIdx.x * 16 + g;
    int e0 = row_ofs[n];
    int e1 = row_ofs[n + 1];
    float acc[8] = {0.f, 0.f, 0.f, 0.f, 0.f, 0.f, 0.f, 0.f};
    int e = e0;
    for (; e + 3 < e1; e += 4) {
        int s0 = csr_src[e], s1 = csr_src[e + 1];
        int s2 = csr_src[e + 2], s3 = csr_src[e + 3];
        half8 v0 = *(const half8*)(p + (size_t)s0 * HD + c * 8);
        half8 v1 = *(const half8*)(p + (size_t)s1 * HD + c * 8);
        half8 v2 = *(const half8*)(p + (size_t)s2 * HD + c * 8);
        half8 v3 = *(const half8*)(p + (size_t)s3 * HD + c * 8);
#pragma unroll
        for (int j = 0; j < 8; ++j)
            acc[j] += ((float)v0[j] + (float)v1[j]) + ((float)v2[j] + (float)v3[j]);
    }
    for (; e < e1; ++e) {
        int s0 = csr_src[e];
        half8 v0 = *(const half8*)(p + (size_t)s0 * HD + c * 8);
#pragma unroll
        for (int j = 0; j < 8; ++j) acc[j] += (float)v0[j];
    }
    float nd = norm_dst[n];
#pragma unroll
    for (int j = 0; j < 8; ++j) {
        float bv = loadT(bias, (size_t)bofs + c * 8 + j, f32);
        float v = fmaxf(acc[j] * nd + bv, 0.0f);
        size_t idx = (size_t)n * HD + c * 8 + j;
        if (is_final) {
            if (f32) ((float*)outv)[idx] = v;
            else ((bf16*)outv)[idx] = __float2bfloat16(v);
        } else {
            h_out[idx] = (fp16)v;
        }
    }
}

extern "C" void kernel_launch(void* const* d_in, const int* in_sizes, int n_in,
                              void* d_out, int out_size, void* d_ws, size_t ws_size,
                              hipStream_t stream) {
    const void* x  = d_in[0];
    const int* src = (const int*)d_in[1];
    const int* dst = (const int*)d_in[2];
    const void* Wp = d_in[3];
    const void* bp = d_in[4];
    const void* Wl = d_in[5];
    const void* bl = d_in[6];

    fp16*  h        = (fp16*)d_ws;                       // NN*HD fp16
    fp16*  p        = h + (size_t)NN * HD;               // NN*HD fp16
    float* norm_src = (float*)(p + (size_t)NN * HD);     // NN
    float* norm_dst = norm_src + NN;                     // NN
    int*   row_ofs  = (int*)(norm_dst + NN);             // NN+1
    int*   cur      = row_ofs + NN + 1;                  // NN
    int*   bsum     = cur + NN;                          // 256
    int*   histo8   = bsum + 256;                        // 8*2*NN
    int*   csr_src  = histo8 + 16 * NN;                  // EE
    int*   flag     = csr_src + EE;                      // 1

    size_t need = (size_t)((char*)(flag + 1) - (char*)d_ws);
    if (ws_size < need) {
        fill_sentinel<<<(out_size + 255) / 256, 256, 0, stream>>>((bf16*)d_out, out_size);
        return;
    }

    const int NB  = (NN + 255) / 256;     // 196
    const int EB4 = (EE + 1023) / 1024;   // 782
    const int EB8 = (EE + 2047) / 2048;   // 391

    detect_kernel<<<1, 64, 0, stream>>>((const unsigned short*)x, flag);
    hipMemsetAsync(histo8, 0, (size_t)16 * NN * sizeof(int), stream);
    degree_kernel<<<EB4, 256, 0, stream>>>(src, dst, histo8);
    norm_scan_kernel<<<NB, 256, 0, stream>>>(histo8, norm_src, norm_dst, row_ofs, bsum);
    scan2_kernel<<<1, 256, 0, stream>>>(bsum, NB);
    scan3_kernel<<<NB, 256, 0, stream>>>(row_ofs, cur, bsum);
    fill_kernel<<<EB8, 256, 0, stream>>>(src, dst, cur, csr_src);

    // h = relu(x @ Wp + bp)
    proj_kernel<<<NN / 16, 256, 0, stream>>>(x, Wp, bp, h, flag);

    for (int l = 0; l < 3; ++l) {
        // p = norm_src ⊙ (h @ Wl)
        pgemm_kernel<<<NN / 16, 256, 0, stream>>>(h, Wl, l * HD * HD, norm_src, flag, p);
        // h_next = relu(norm_dst ⊙ (A @ p) + bl)   [A = adjacency via CSR]
        gather_kernel<<<NN / 16, 256, 0, stream>>>(
            p, row_ofs, csr_src, norm_dst, bl, l * HD, flag,
            h, d_out, (l == 2) ? 1 : 0);
    }
}

// Round 9
// 519.668 us; speedup vs baseline: 1.0001x; 1.0001x over previous
//
#include <hip/hip_runtime.h>
#include <hip/hip_bf16.h>

#define NN 50000
#define EE 800000
#define IND 64
#define HD 128

#define KCH 32            // edge chunks
#define CHUNK 25000       // EE / KCH
#define HALF_N 25000      // NN / 2
#define HWORDS 12500      // HALF_N / 2 (16-bit packed pairs)

typedef __hip_bfloat16 bf16;
typedef _Float16 fp16;
typedef _Float16 half8 __attribute__((ext_vector_type(8)));

__device__ __forceinline__ float loadT(const void* p, size_t i, int f32) {
    if (f32) return ((const float*)p)[i];
    return __bfloat162float(((const bf16*)p)[i]);
}

// flag=1 if float inputs are fp32, flag=0 if bf16.
__global__ void detect_kernel(const unsigned short* __restrict__ xraw,
                              int* __restrict__ flag) {
    if (threadIdx.x == 0) {
        int f = 0;
        for (int i = 0; i < 256; i += 2) {
            unsigned int w = ((unsigned int)xraw[i]) << 16;
            float a = fabsf(__uint_as_float(w));
            if (!(a <= 1.0e6f)) f = 1;
        }
        *flag = f;
    }
}

__global__ void fill_sentinel(bf16* __restrict__ out, int n) {
    int i = blockIdx.x * 256 + threadIdx.x;
    if (i < n) out[i] = __float2bfloat16(0.123f);
}

// Chunked LDS histograms, zero global atomics.
// grid 128: b>>6 = stream (0: dst->PD, 1: src->PS); (b>>5)&1 = node half; b&31 = chunk.
// 16-bit packed counters: per-(chunk,half) count <= 25000 < 2^16, no carry across halves.
__global__ __launch_bounds__(256) void histA_kernel(const int* __restrict__ src,
                                                    const int* __restrict__ dst,
                                                    unsigned* __restrict__ PD,
                                                    unsigned* __restrict__ PS) {
    int b = blockIdx.x;
    int stream = b >> 6;
    int half = (b >> 5) & 1;
    int k = b & 31;
    const int* ebuf = stream ? src : dst;
    unsigned* out = (stream ? PS : PD) + (size_t)(k * 2 + half) * HWORDS;
    __shared__ unsigned sh[HWORDS];
    for (int w = threadIdx.x; w < HWORDS; w += 256) sh[w] = 0;
    __syncthreads();
    int base = k * CHUNK;
    int hb = half * HALF_N;
    for (int i = threadIdx.x; i < CHUNK; i += 256) {
        int n = ebuf[base + i];
        unsigned r = (unsigned)(n - hb);
        if (r < HALF_N)
            atomicAdd(&sh[r >> 1], 1u << ((r & 1) * 16));
    }
    __syncthreads();
    for (int w = threadIdx.x; w < HWORDS; w += 256) out[w] = sh[w];
}

// Sum chunk partials -> degrees -> norms; block-scan deg_in -> row_ofs chunk + bsum.
__global__ __launch_bounds__(256) void normscanB_kernel(const unsigned* __restrict__ PD,
                                                        const unsigned* __restrict__ PS,
                                                        float* __restrict__ norm_src,
                                                        float* __restrict__ norm_dst,
                                                        int* __restrict__ row_ofs,
                                                        int* __restrict__ bsum) {
    __shared__ int sm[256];
    int t = threadIdx.x;
    int i = blockIdx.x * 256 + t;
    int d = 0;
    if (i < NN) {
        int half = (i >= HALF_N) ? 1 : 0;
        unsigned r = (unsigned)(i - half * HALF_N);
        int w = r >> 1, shf = (r & 1) * 16;
        int s = 0;
#pragma unroll
        for (int k = 0; k < KCH; ++k) {
            d += (PD[(size_t)(k * 2 + half) * HWORDS + w] >> shf) & 0xffff;
            s += (PS[(size_t)(k * 2 + half) * HWORDS + w] >> shf) & 0xffff;
        }
        norm_src[i] = rsqrtf((float)(s < 1 ? 1 : s));
        norm_dst[i] = rsqrtf((float)(d < 1 ? 1 : d));
    }
    sm[t] = d;
    __syncthreads();
    for (int ofs = 1; ofs < 256; ofs <<= 1) {
        int add = (t >= ofs) ? sm[t - ofs] : 0;
        __syncthreads();
        sm[t] += add;
        __syncthreads();
    }
    if (i < NN) row_ofs[i] = sm[t] - d;
    if (t == 255) bsum[blockIdx.x] = sm[255];
}

__global__ __launch_bounds__(256) void scan2_kernel(int* __restrict__ bsum, int nb) {
    __shared__ int s[256];
    int t = threadIdx.x;
    int v = (t < nb) ? bsum[t] : 0;
    s[t] = v;
    __syncthreads();
    for (int ofs = 1; ofs < 256; ofs <<= 1) {
        int add = (t >= ofs) ? s[t - ofs] : 0;
        __syncthreads();
        s[t] += add;
        __syncthreads();
    }
    if (t < nb) bsum[t] = s[t] - v;
}

// Finalize row_ofs; emit per-chunk bucket cursors start[k][n].
__global__ __launch_bounds__(256) void scan3_kernel(int* __restrict__ row_ofs,
                                                    const int* __restrict__ bsum,
                                                    const unsigned* __restrict__ PD,
                                                    int* __restrict__ start) {
    int t = threadIdx.x;
    int i = blockIdx.x * 256 + t;
    if (i < NN) {
        int v = row_ofs[i] + bsum[blockIdx.x];
        row_ofs[i] = v;
        int half = (i >= HALF_N) ? 1 : 0;
        unsigned r = (unsigned)(i - half * HALF_N);
        int w = r >> 1, shf = (r & 1) * 16;
        int run = v;
#pragma unroll
        for (int k = 0; k < KCH; ++k) {
            start[(size_t)k * NN + i] = run;
            run += (PD[(size_t)(k * 2 + half) * HWORDS + w] >> shf) & 0xffff;
        }
    }
    if (i == 0) row_ofs[NN] = EE;
}

// CSR placement: LDS atomic gives intra-chunk rank; pos = start[k][dst] + rank.
// Unique by construction (start partitions each bucket by chunk). No global atomics.
__global__ __launch_bounds__(256) void placeC_kernel(const int* __restrict__ src,
                                                     const int* __restrict__ dst,
                                                     const int* __restrict__ start,
                                                     int* __restrict__ csr_src) {
    int b = blockIdx.x;
    int half = b >> 5;
    int k = b & 31;
    __shared__ unsigned sh[HWORDS];
    for (int w = threadIdx.x; w < HWORDS; w += 256) sh[w] = 0;
    __syncthreads();
    int base = k * CHUNK;
    int hb = half * HALF_N;
    for (int i = threadIdx.x; i < CHUNK; i += 256) {
        int n = dst[base + i];
        unsigned r = (unsigned)(n - hb);
        if (r < HALF_N) {
            unsigned shf = (r & 1) * 16;
            unsigned old = atomicAdd(&sh[r >> 1], 1u << shf);
            int local = (int)((old >> shf) & 0xffff);
            int pos = start[(size_t)k * NN + n] + local;
            csr_src[pos] = src[base + i];
        }
    }
}

// ===== compute path: verbatim from round 8 (proven) =====

// h[row,j] = fp16( relu(x @ Wp + bp) ); 16 rows/block.
__global__ __launch_bounds__(256) void proj_kernel(const void* __restrict__ x,
                                                   const void* __restrict__ Wp,
                                                   const void* __restrict__ bp,
                                                   fp16* __restrict__ h,
                                                   const int* __restrict__ flag) {
    int f32 = *flag;
    __shared__ float xs[16 * IND];
    int row0 = blockIdx.x * 16;
    for (int i = threadIdx.x; i < 16 * IND; i += 256) {
        int r = i >> 6, c = i & 63;
        xs[i] = loadT(x, (size_t)(row0 + r) * IND + c, f32);
    }
    __syncthreads();
    int j = threadIdx.x & 127;
    int rr = threadIdx.x >> 7;
    float acc[8] = {0.f, 0.f, 0.f, 0.f, 0.f, 0.f, 0.f, 0.f};
    for (int k = 0; k < IND; ++k) {
        float w = loadT(Wp, (size_t)k * HD + j, f32);
#pragma unroll
        for (int r = 0; r < 8; ++r) acc[r] += xs[(rr * 8 + r) * IND + k] * w;
    }
    float b = loadT(bp, j, f32);
#pragma unroll
    for (int r = 0; r < 8; ++r) {
        int row = row0 + rr * 8 + r;
        h[(size_t)row * HD + j] = (fp16)fmaxf(acc[r] + b, 0.0f);
    }
}

// p[row,:] = norm_src[row] * (h[row,:] @ W)
__global__ __launch_bounds__(256) void pgemm_kernel(const fp16* __restrict__ h,
                                                    const void* __restrict__ W,
                                                    int wofs,
                                                    const float* __restrict__ norm_src,
                                                    const int* __restrict__ flag,
                                                    fp16* __restrict__ p) {
    int f32 = *flag;
    __shared__ float as[16 * HD];
    int row0 = blockIdx.x * 16;
    for (int i = threadIdx.x; i < 16 * HD; i += 256) {
        int r = i >> 7;
        as[i] = (float)h[(size_t)(row0 + r) * HD + (i & 127)];
    }
    __syncthreads();
    int j = threadIdx.x & 127;
    int rr = threadIdx.x >> 7;
    float acc[8] = {0.f, 0.f, 0.f, 0.f, 0.f, 0.f, 0.f, 0.f};
    for (int k = 0; k < HD; ++k) {
        float w = loadT(W, (size_t)wofs + (size_t)k * HD + j, f32);
#pragma unroll
        for (int r = 0; r < 8; ++r) acc[r] += as[(rr * 8 + r) * HD + k] * w;
    }
#pragma unroll
    for (int r = 0; r < 8; ++r) {
        int row = row0 + rr * 8 + r;
        p[(size_t)row * HD + j] = (fp16)(acc[r] * norm_src[row]);
    }
}

// out[n,:] = relu(norm_dst[n] * sum_e p[csr_src[e],:] + bias)
__global__ __launch_bounds__(256) void gather_kernel(const fp16* __restrict__ p,
                                                     const int* __restrict__ row_ofs,
                                                     const int* __restrict__ csr_src,
                                                     const float* __restrict__ norm_dst,
                                                     const void* __restrict__ bias,
                                                     int bofs,
                                                     const int* __restrict__ flag,
                                                     fp16* __restrict__ h_out,
                                                     void* __restrict__ outv,
                                                     int is_final) {
    int f32 = *flag;
    int g = threadIdx.x >> 4;
    int c = threadIdx.x & 15;
    int n = blockIdx.x * 16 + g;
    int e0 = row_ofs[n];
    int e1 = row_ofs[n + 1];
    float acc[8] = {0.f, 0.f, 0.f, 0.f, 0.f, 0.f, 0.f, 0.f};
    int e = e0;
    for (; e + 3 < e1; e += 4) {
        int s0 = csr_src[e], s1 = csr_src[e + 1];
        int s2 = csr_src[e + 2], s3 = csr_src[e + 3];
        half8 v0 = *(const half8*)(p + (size_t)s0 * HD + c * 8);
        half8 v1 = *(const half8*)(p + (size_t)s1 * HD + c * 8);
        half8 v2 = *(const half8*)(p + (size_t)s2 * HD + c * 8);
        half8 v3 = *(const half8*)(p + (size_t)s3 * HD + c * 8);
#pragma unroll
        for (int j = 0; j < 8; ++j)
            acc[j] += ((float)v0[j] + (float)v1[j]) + ((float)v2[j] + (float)v3[j]);
    }
    for (; e < e1; ++e) {
        int s0 = csr_src[e];
        half8 v0 = *(const half8*)(p + (size_t)s0 * HD + c * 8);
#pragma unroll
        for (int j = 0; j < 8; ++j) acc[j] += (float)v0[j];
    }
    float nd = norm_dst[n];
#pragma unroll
    for (int j = 0; j < 8; ++j) {
        float bv = loadT(bias, (size_t)bofs + c * 8 + j, f32);
        float v = fmaxf(acc[j] * nd + bv, 0.0f);
        size_t idx = (size_t)n * HD + c * 8 + j;
        if (is_final) {
            if (f32) ((float*)outv)[idx] = v;
            else ((bf16*)outv)[idx] = __float2bfloat16(v);
        } else {
            h_out[idx] = (fp16)v;
        }
    }
}

extern "C" void kernel_launch(void* const* d_in, const int* in_sizes, int n_in,
                              void* d_out, int out_size, void* d_ws, size_t ws_size,
                              hipStream_t stream) {
    const void* x  = d_in[0];
    const int* src = (const int*)d_in[1];
    const int* dst = (const int*)d_in[2];
    const void* Wp = d_in[3];
    const void* bp = d_in[4];
    const void* Wl = d_in[5];
    const void* bl = d_in[6];

    fp16*     h        = (fp16*)d_ws;                        // NN*HD fp16
    fp16*     p        = h + (size_t)NN * HD;                // NN*HD fp16
    float*    norm_src = (float*)(p + (size_t)NN * HD);      // NN
    float*    norm_dst = norm_src + NN;                      // NN
    int*      row_ofs  = (int*)(norm_dst + NN);              // NN+1
    int*      bsum     = row_ofs + NN + 1;                   // 256
    unsigned* PD       = (unsigned*)(bsum + 256);            // KCH*2*HWORDS
    unsigned* PS       = PD + (size_t)KCH * 2 * HWORDS;      // KCH*2*HWORDS
    int*      start    = (int*)(PS + (size_t)KCH * 2 * HWORDS); // KCH*NN
    int*      csr_src  = start + (size_t)KCH * NN;           // EE
    int*      flag     = csr_src + EE;                       // 1

    size_t need = (size_t)((char*)(flag + 1) - (char*)d_ws);
    if (ws_size < need) {
        fill_sentinel<<<(out_size + 255) / 256, 256, 0, stream>>>((bf16*)d_out, out_size);
        return;
    }

    const int NB = (NN + 255) / 256;  // 196

    detect_kernel<<<1, 64, 0, stream>>>((const unsigned short*)x, flag);
    histA_kernel<<<128, 256, 0, stream>>>(src, dst, PD, PS);
    normscanB_kernel<<<NB, 256, 0, stream>>>(PD, PS, norm_src, norm_dst, row_ofs, bsum);
    scan2_kernel<<<1, 256, 0, stream>>>(bsum, NB);
    scan3_kernel<<<NB, 256, 0, stream>>>(row_ofs, bsum, PD, start);
    placeC_kernel<<<64, 256, 0, stream>>>(src, dst, start, csr_src);

    // h = relu(x @ Wp + bp)
    proj_kernel<<<NN / 16, 256, 0, stream>>>(x, Wp, bp, h, flag);

    for (int l = 0; l < 3; ++l) {
        // p = norm_src ⊙ (h @ Wl)
        pgemm_kernel<<<NN / 16, 256, 0, stream>>>(h, Wl, l * HD * HD, norm_src, flag, p);
        // h_next = relu(norm_dst ⊙ (A @ p) + bl)
        gather_kernel<<<NN / 16, 256, 0, stream>>>(
            p, row_ofs, csr_src, norm_dst, bl, l * HD, flag,
            h, d_out, (l == 2) ? 1 : 0);
    }
}

// Round 10
// 439.592 us; speedup vs baseline: 1.1823x; 1.1822x over previous
//
#include <hip/hip_runtime.h>
#include <hip/hip_bf16.h>

#define NN 50000
#define EE 800000
#define IND 64
#define HD 128

#define KCH 32            // edge chunks
#define CHUNK 25000       // EE / KCH
#define HALF_N 25000      // NN / 2
#define HWORDS 12500      // HALF_N / 2 (16-bit packed pairs)

typedef __hip_bfloat16 bf16;
typedef _Float16 fp16;
typedef _Float16 half8 __attribute__((ext_vector_type(8)));
typedef __attribute__((ext_vector_type(4))) float f32x4;

__device__ __forceinline__ float loadT(const void* p, size_t i, int f32) {
    if (f32) return ((const float*)p)[i];
    return __bfloat162float(((const bf16*)p)[i]);
}

// flag=1 if float inputs are fp32, flag=0 if bf16.
__global__ void detect_kernel(const unsigned short* __restrict__ xraw,
                              int* __restrict__ flag) {
    if (threadIdx.x == 0) {
        int f = 0;
        for (int i = 0; i < 256; i += 2) {
            unsigned int w = ((unsigned int)xraw[i]) << 16;
            float a = fabsf(__uint_as_float(w));
            if (!(a <= 1.0e6f)) f = 1;
        }
        *flag = f;
    }
}

__global__ void fill_sentinel(bf16* __restrict__ out, int n) {
    int i = blockIdx.x * 256 + threadIdx.x;
    if (i < n) out[i] = __float2bfloat16(0.123f);
}

// Chunked LDS histograms, zero global atomics.
__global__ __launch_bounds__(256) void histA_kernel(const int* __restrict__ src,
                                                    const int* __restrict__ dst,
                                                    unsigned* __restrict__ PD,
                                                    unsigned* __restrict__ PS) {
    int b = blockIdx.x;
    int stream = b >> 6;
    int half = (b >> 5) & 1;
    int k = b & 31;
    const int* ebuf = stream ? src : dst;
    unsigned* out = (stream ? PS : PD) + (size_t)(k * 2 + half) * HWORDS;
    __shared__ unsigned sh[HWORDS];
    for (int w = threadIdx.x; w < HWORDS; w += 256) sh[w] = 0;
    __syncthreads();
    int base = k * CHUNK;
    int hb = half * HALF_N;
    for (int i = threadIdx.x; i < CHUNK; i += 256) {
        int n = ebuf[base + i];
        unsigned r = (unsigned)(n - hb);
        if (r < HALF_N)
            atomicAdd(&sh[r >> 1], 1u << ((r & 1) * 16));
    }
    __syncthreads();
    for (int w = threadIdx.x; w < HWORDS; w += 256) out[w] = sh[w];
}

// Sum chunk partials -> degrees -> norms; block-scan deg_in.
__global__ __launch_bounds__(256) void normscanB_kernel(const unsigned* __restrict__ PD,
                                                        const unsigned* __restrict__ PS,
                                                        float* __restrict__ norm_src,
                                                        float* __restrict__ norm_dst,
                                                        int* __restrict__ row_ofs,
                                                        int* __restrict__ bsum) {
    __shared__ int sm[256];
    int t = threadIdx.x;
    int i = blockIdx.x * 256 + t;
    int d = 0;
    if (i < NN) {
        int half = (i >= HALF_N) ? 1 : 0;
        unsigned r = (unsigned)(i - half * HALF_N);
        int w = r >> 1, shf = (r & 1) * 16;
        int s = 0;
#pragma unroll
        for (int k = 0; k < KCH; ++k) {
            d += (PD[(size_t)(k * 2 + half) * HWORDS + w] >> shf) & 0xffff;
            s += (PS[(size_t)(k * 2 + half) * HWORDS + w] >> shf) & 0xffff;
        }
        norm_src[i] = rsqrtf((float)(s < 1 ? 1 : s));
        norm_dst[i] = rsqrtf((float)(d < 1 ? 1 : d));
    }
    sm[t] = d;
    __syncthreads();
    for (int ofs = 1; ofs < 256; ofs <<= 1) {
        int add = (t >= ofs) ? sm[t - ofs] : 0;
        __syncthreads();
        sm[t] += add;
        __syncthreads();
    }
    if (i < NN) row_ofs[i] = sm[t] - d;
    if (t == 255) bsum[blockIdx.x] = sm[255];
}

__global__ __launch_bounds__(256) void scan2_kernel(int* __restrict__ bsum, int nb) {
    __shared__ int s[256];
    int t = threadIdx.x;
    int v = (t < nb) ? bsum[t] : 0;
    s[t] = v;
    __syncthreads();
    for (int ofs = 1; ofs < 256; ofs <<= 1) {
        int add = (t >= ofs) ? s[t - ofs] : 0;
        __syncthreads();
        s[t] += add;
        __syncthreads();
    }
    if (t < nb) bsum[t] = s[t] - v;
}

// Finalize row_ofs; emit per-chunk bucket cursors start[k][n].
__global__ __launch_bounds__(256) void scan3_kernel(int* __restrict__ row_ofs,
                                                    const int* __restrict__ bsum,
                                                    const unsigned* __restrict__ PD,
                                                    int* __restrict__ start) {
    int t = threadIdx.x;
    int i = blockIdx.x * 256 + t;
    if (i < NN) {
        int v = row_ofs[i] + bsum[blockIdx.x];
        row_ofs[i] = v;
        int half = (i >= HALF_N) ? 1 : 0;
        unsigned r = (unsigned)(i - half * HALF_N);
        int w = r >> 1, shf = (r & 1) * 16;
        int run = v;
#pragma unroll
        for (int k = 0; k < KCH; ++k) {
            start[(size_t)k * NN + i] = run;
            run += (PD[(size_t)(k * 2 + half) * HWORDS + w] >> shf) & 0xffff;
        }
    }
    if (i == 0) row_ofs[NN] = EE;
}

// CSR placement via LDS rank; no global atomics.
__global__ __launch_bounds__(256) void placeC_kernel(const int* __restrict__ src,
                                                     const int* __restrict__ dst,
                                                     const int* __restrict__ start,
                                                     int* __restrict__ csr_src) {
    int b = blockIdx.x;
    int half = b >> 5;
    int k = b & 31;
    __shared__ unsigned sh[HWORDS];
    for (int w = threadIdx.x; w < HWORDS; w += 256) sh[w] = 0;
    __syncthreads();
    int base = k * CHUNK;
    int hb = half * HALF_N;
    for (int i = threadIdx.x; i < CHUNK; i += 256) {
        int n = dst[base + i];
        unsigned r = (unsigned)(n - hb);
        if (r < HALF_N) {
            unsigned shf = (r & 1) * 16;
            unsigned old = atomicAdd(&sh[r >> 1], 1u << shf);
            int local = (int)((old >> shf) & 0xffff);
            int pos = start[(size_t)k * NN + n] + local;
            csr_src[pos] = src[base + i];
        }
    }
}

// h[row,j] = fp16( relu(x @ Wp + bp) ); 16 rows/block.  [R8-proven]
__global__ __launch_bounds__(256) void proj_kernel(const void* __restrict__ x,
                                                   const void* __restrict__ Wp,
                                                   const void* __restrict__ bp,
                                                   fp16* __restrict__ h,
                                                   const int* __restrict__ flag) {
    int f32 = *flag;
    __shared__ float xs[16 * IND];
    int row0 = blockIdx.x * 16;
    for (int i = threadIdx.x; i < 16 * IND; i += 256) {
        int r = i >> 6, c = i & 63;
        xs[i] = loadT(x, (size_t)(row0 + r) * IND + c, f32);
    }
    __syncthreads();
    int j = threadIdx.x & 127;
    int rr = threadIdx.x >> 7;
    float acc[8] = {0.f, 0.f, 0.f, 0.f, 0.f, 0.f, 0.f, 0.f};
    for (int k = 0; k < IND; ++k) {
        float w = loadT(Wp, (size_t)k * HD + j, f32);
#pragma unroll
        for (int r = 0; r < 8; ++r) acc[r] += xs[(rr * 8 + r) * IND + k] * w;
    }
    float b = loadT(bp, j, f32);
#pragma unroll
    for (int r = 0; r < 8; ++r) {
        int row = row0 + rr * 8 + r;
        h[(size_t)row * HD + j] = (fp16)fmaxf(acc[r] + b, 0.0f);
    }
}

// *** THE ONE CHANGE vs round 9 ***
// p[row,:] = norm_src[row] * (h[row,:] @ W)  via mfma_f32_16x16x32_f16.
// 64 rows/block (4 waves x 16 rows). W^T staged fp16 in LDS (stride 136).
// A-frag: lane(m=lane&15,q=lane>>4) holds h[row0+m][q*8+j+kk*32]  [m120]
// B-frag: lane holds W[q*8+j+kk*32][t*16+m] = wt[(t*16+m)*136 + ...]
// C/D: col=lane&15, row=q*4+reg  [m89; dtype-independent per m121/m123]
__global__ __launch_bounds__(256) void pgemm_kernel(const fp16* __restrict__ h,
                                                    const void* __restrict__ W,
                                                    int wofs,
                                                    const float* __restrict__ norm_src,
                                                    const int* __restrict__ flag,
                                                    fp16* __restrict__ p) {
    int f32 = *flag;
    __shared__ fp16 wt[128 * 136];
    int tid = threadIdx.x;
    for (int idx = tid; idx < 128 * 128; idx += 256) {
        int k = idx >> 7, n = idx & 127;
        wt[n * 136 + k] = (fp16)loadT(W, (size_t)wofs + (size_t)k * 128 + n, f32);
    }
    __syncthreads();

    int w = tid >> 6;
    int lane = tid & 63;
    int m = lane & 15;
    int q = lane >> 4;
    int row0 = blockIdx.x * 64 + w * 16;

    int rowA = row0 + m;
    if (rowA > NN - 1) rowA = NN - 1;
    const fp16* Arow = h + (size_t)rowA * 128 + q * 8;
    half8 a[4];
#pragma unroll
    for (int kk = 0; kk < 4; ++kk) a[kk] = *(const half8*)(Arow + kk * 32);

    float ns[4];
#pragma unroll
    for (int r = 0; r < 4; ++r) {
        int row = row0 + q * 4 + r;
        ns[r] = norm_src[row < NN ? row : NN - 1];
    }

#pragma unroll
    for (int t = 0; t < 8; ++t) {
        f32x4 c = {0.f, 0.f, 0.f, 0.f};
        const fp16* bt = &wt[(t * 16 + m) * 136 + q * 8];
#pragma unroll
        for (int kk = 0; kk < 4; ++kk) {
            half8 b = *(const half8*)(bt + kk * 32);
            c = __builtin_amdgcn_mfma_f32_16x16x32_f16(a[kk], b, c, 0, 0, 0);
        }
        int col = t * 16 + m;
#pragma unroll
        for (int r = 0; r < 4; ++r) {
            int row = row0 + q * 4 + r;
            if (row < NN)
                p[(size_t)row * 128 + col] = (fp16)(c[r] * ns[r]);
        }
    }
}

// out[n,:] = relu(norm_dst[n] * sum_e p[csr_src[e],:] + bias)  [R8-proven]
__global__ __launch_bounds__(256) void gather_kernel(const fp16* __restrict__ p,
                                                     const int* __restrict__ row_ofs,
                                                     const int* __restrict__ csr_src,
                                                     const float* __restrict__ norm_dst,
                                                     const void* __restrict__ bias,
                                                     int bofs,
                                                     const int* __restrict__ flag,
                                                     fp16* __restrict__ h_out,
                                                     void* __restrict__ outv,
                                                     int is_final) {
    int f32 = *flag;
    int g = threadIdx.x >> 4;
    int c = threadIdx.x & 15;
    int n = blockIdx.x * 16 + g;
    int e0 = row_ofs[n];
    int e1 = row_ofs[n + 1];
    float acc[8] = {0.f, 0.f, 0.f, 0.f, 0.f, 0.f, 0.f, 0.f};
    int e = e0;
    for (; e + 3 < e1; e += 4) {
        int s0 = csr_src[e], s1 = csr_src[e + 1];
        int s2 = csr_src[e + 2], s3 = csr_src[e + 3];
        half8 v0 = *(const half8*)(p + (size_t)s0 * HD + c * 8);
        half8 v1 = *(const half8*)(p + (size_t)s1 * HD + c * 8);
        half8 v2 = *(const half8*)(p + (size_t)s2 * HD + c * 8);
        half8 v3 = *(const half8*)(p + (size_t)s3 * HD + c * 8);
#pragma unroll
        for (int j = 0; j < 8; ++j)
            acc[j] += ((float)v0[j] + (float)v1[j]) + ((float)v2[j] + (float)v3[j]);
    }
    for (; e < e1; ++e) {
        int s0 = csr_src[e];
        half8 v0 = *(const half8*)(p + (size_t)s0 * HD + c * 8);
#pragma unroll
        for (int j = 0; j < 8; ++j) acc[j] += (float)v0[j];
    }
    float nd = norm_dst[n];
#pragma unroll
    for (int j = 0; j < 8; ++j) {
        float bv = loadT(bias, (size_t)bofs + c * 8 + j, f32);
        float v = fmaxf(acc[j] * nd + bv, 0.0f);
        size_t idx = (size_t)n * HD + c * 8 + j;
        if (is_final) {
            if (f32) ((float*)outv)[idx] = v;
            else ((bf16*)outv)[idx] = __float2bfloat16(v);
        } else {
            h_out[idx] = (fp16)v;
        }
    }
}

extern "C" void kernel_launch(void* const* d_in, const int* in_sizes, int n_in,
                              void* d_out, int out_size, void* d_ws, size_t ws_size,
                              hipStream_t stream) {
    const void* x  = d_in[0];
    const int* src = (const int*)d_in[1];
    const int* dst = (const int*)d_in[2];
    const void* Wp = d_in[3];
    const void* bp = d_in[4];
    const void* Wl = d_in[5];
    const void* bl = d_in[6];

    fp16*     h        = (fp16*)d_ws;                        // NN*HD fp16
    fp16*     p        = h + (size_t)NN * HD;                // NN*HD fp16
    float*    norm_src = (float*)(p + (size_t)NN * HD);      // NN
    float*    norm_dst = norm_src + NN;                      // NN
    int*      row_ofs  = (int*)(norm_dst + NN);              // NN+1
    int*      bsum     = row_ofs + NN + 1;                   // 256
    unsigned* PD       = (unsigned*)(bsum + 256);            // KCH*2*HWORDS
    unsigned* PS       = PD + (size_t)KCH * 2 * HWORDS;      // KCH*2*HWORDS
    int*      start    = (int*)(PS + (size_t)KCH * 2 * HWORDS); // KCH*NN
    int*      csr_src  = start + (size_t)KCH * NN;           // EE
    int*      flag     = csr_src + EE;                       // 1

    size_t need = (size_t)((char*)(flag + 1) - (char*)d_ws);
    if (ws_size < need) {
        fill_sentinel<<<(out_size + 255) / 256, 256, 0, stream>>>((bf16*)d_out, out_size);
        return;
    }

    const int NB = (NN + 255) / 256;  // 196

    detect_kernel<<<1, 64, 0, stream>>>((const unsigned short*)x, flag);
    histA_kernel<<<128, 256, 0, stream>>>(src, dst, PD, PS);
    normscanB_kernel<<<NB, 256, 0, stream>>>(PD, PS, norm_src, norm_dst, row_ofs, bsum);
    scan2_kernel<<<1, 256, 0, stream>>>(bsum, NB);
    scan3_kernel<<<NB, 256, 0, stream>>>(row_ofs, bsum, PD, start);
    placeC_kernel<<<64, 256, 0, stream>>>(src, dst, start, csr_src);

    // h = relu(x @ Wp + bp)
    proj_kernel<<<NN / 16, 256, 0, stream>>>(x, Wp, bp, h, flag);

    for (int l = 0; l < 3; ++l) {
        // p = norm_src ⊙ (h @ Wl)   [MFMA]
        pgemm_kernel<<<(NN + 63) / 64, 256, 0, stream>>>(h, Wl, l * HD * HD, norm_src, flag, p);
        // h_next = relu(norm_dst ⊙ (A @ p) + bl)
        gather_kernel<<<NN / 16, 256, 0, stream>>>(
            p, row_ofs, csr_src, norm_dst, bl, l * HD, flag,
            h, d_out, (l == 2) ? 1 : 0);
    }
}

// Round 11
// 414.423 us; speedup vs baseline: 1.2541x; 1.0607x over previous
//
#include <hip/hip_runtime.h>
#include <hip/hip_bf16.h>

#define NN 50000
#define EE 800000
#define IND 64
#define HD 128

#define KCH 64            // edge chunks
#define CHUNK 12500       // EE / KCH
#define NPART 4           // node partitions
#define PART_N 12500      // NN / NPART
#define PWORDS 6250       // PART_N / 2 (16-bit packed pairs)

typedef __hip_bfloat16 bf16;
typedef _Float16 fp16;
typedef _Float16 half8 __attribute__((ext_vector_type(8)));
typedef __attribute__((ext_vector_type(4))) float f32x4;

__device__ __forceinline__ float loadT(const void* p, size_t i, int f32) {
    if (f32) return ((const float*)p)[i];
    return __bfloat162float(((const bf16*)p)[i]);
}

// flag=1 if float inputs are fp32, flag=0 if bf16.
__global__ void detect_kernel(const unsigned short* __restrict__ xraw,
                              int* __restrict__ flag) {
    if (threadIdx.x == 0) {
        int f = 0;
        for (int i = 0; i < 256; i += 2) {
            unsigned int w = ((unsigned int)xraw[i]) << 16;
            float a = fabsf(__uint_as_float(w));
            if (!(a <= 1.0e6f)) f = 1;
        }
        *flag = f;
    }
}

__global__ void fill_sentinel(bf16* __restrict__ out, int n) {
    int i = blockIdx.x * 256 + threadIdx.x;
    if (i < n) out[i] = __float2bfloat16(0.123f);
}

// Chunked LDS histograms, zero global atomics.
// grid 512: b>>8 = stream (0: dst->PD, 1: src->PS); (b>>6)&3 = partition; b&63 = chunk.
// 25 KB LDS/block -> high residency; 16-bit packed (count <= CHUNK=12500 < 2^16).
__global__ __launch_bounds__(256) void histA_kernel(const int* __restrict__ src,
                                                    const int* __restrict__ dst,
                                                    unsigned* __restrict__ PD,
                                                    unsigned* __restrict__ PS) {
    int b = blockIdx.x;
    int stream = b >> 8;
    int part = (b >> 6) & 3;
    int k = b & 63;
    const int* ebuf = stream ? src : dst;
    unsigned* out = (stream ? PS : PD) + (size_t)(k * NPART + part) * PWORDS;
    __shared__ unsigned sh[PWORDS];
    for (int w = threadIdx.x; w < PWORDS; w += 256) sh[w] = 0;
    __syncthreads();
    int base = k * CHUNK;
    int pb = part * PART_N;
    for (int i = threadIdx.x; i < CHUNK; i += 256) {
        int n = ebuf[base + i];
        unsigned r = (unsigned)(n - pb);
        if (r < PART_N)
            atomicAdd(&sh[r >> 1], 1u << ((r & 1) * 16));
    }
    __syncthreads();
    for (int w = threadIdx.x; w < PWORDS; w += 256) out[w] = sh[w];
}

// Sum chunk partials -> degrees -> norms; block-scan deg_in.
__global__ __launch_bounds__(256) void normscanB_kernel(const unsigned* __restrict__ PD,
                                                        const unsigned* __restrict__ PS,
                                                        float* __restrict__ norm_src,
                                                        float* __restrict__ norm_dst,
                                                        int* __restrict__ row_ofs,
                                                        int* __restrict__ bsum) {
    __shared__ int sm[256];
    int t = threadIdx.x;
    int i = blockIdx.x * 256 + t;
    int d = 0;
    if (i < NN) {
        int part = i / PART_N;
        unsigned r = (unsigned)(i - part * PART_N);
        int w = r >> 1, shf = (r & 1) * 16;
        int s = 0;
#pragma unroll
        for (int k = 0; k < KCH; ++k) {
            d += (PD[(size_t)(k * NPART + part) * PWORDS + w] >> shf) & 0xffff;
            s += (PS[(size_t)(k * NPART + part) * PWORDS + w] >> shf) & 0xffff;
        }
        norm_src[i] = rsqrtf((float)(s < 1 ? 1 : s));
        norm_dst[i] = rsqrtf((float)(d < 1 ? 1 : d));
    }
    sm[t] = d;
    __syncthreads();
    for (int ofs = 1; ofs < 256; ofs <<= 1) {
        int add = (t >= ofs) ? sm[t - ofs] : 0;
        __syncthreads();
        sm[t] += add;
        __syncthreads();
    }
    if (i < NN) row_ofs[i] = sm[t] - d;
    if (t == 255) bsum[blockIdx.x] = sm[255];
}

__global__ __launch_bounds__(256) void scan2_kernel(int* __restrict__ bsum, int nb) {
    __shared__ int s[256];
    int t = threadIdx.x;
    int v = (t < nb) ? bsum[t] : 0;
    s[t] = v;
    __syncthreads();
    for (int ofs = 1; ofs < 256; ofs <<= 1) {
        int add = (t >= ofs) ? s[t - ofs] : 0;
        __syncthreads();
        s[t] += add;
        __syncthreads();
    }
    if (t < nb) bsum[t] = s[t] - v;
}

// Finalize row_ofs; emit per-chunk absolute bucket cursors start[k][n].
__global__ __launch_bounds__(256) void scan3_kernel(int* __restrict__ row_ofs,
                                                    const int* __restrict__ bsum,
                                                    const unsigned* __restrict__ PD,
                                                    int* __restrict__ start) {
    int t = threadIdx.x;
    int i = blockIdx.x * 256 + t;
    if (i < NN) {
        int v = row_ofs[i] + bsum[blockIdx.x];
        row_ofs[i] = v;
        int part = i / PART_N;
        unsigned r = (unsigned)(i - part * PART_N);
        int w = r >> 1, shf = (r & 1) * 16;
        int run = v;
#pragma unroll
        for (int k = 0; k < KCH; ++k) {
            start[(size_t)k * NN + i] = run;
            run += (PD[(size_t)(k * NPART + part) * PWORDS + w] >> shf) & 0xffff;
        }
    }
    if (i == 0) row_ofs[NN] = EE;
}

// CSR placement via LDS rank; no global atomics.
// grid 256: b>>6 = partition; b&63 = chunk. 25 KB LDS.
__global__ __launch_bounds__(256) void placeC_kernel(const int* __restrict__ src,
                                                     const int* __restrict__ dst,
                                                     const int* __restrict__ start,
                                                     int* __restrict__ csr_src) {
    int b = blockIdx.x;
    int part = b >> 6;
    int k = b & 63;
    __shared__ unsigned sh[PWORDS];
    for (int w = threadIdx.x; w < PWORDS; w += 256) sh[w] = 0;
    __syncthreads();
    int base = k * CHUNK;
    int pb = part * PART_N;
    for (int i = threadIdx.x; i < CHUNK; i += 256) {
        int n = dst[base + i];
        unsigned r = (unsigned)(n - pb);
        if (r < PART_N) {
            unsigned shf = (r & 1) * 16;
            unsigned old = atomicAdd(&sh[r >> 1], 1u << shf);
            int local = (int)((old >> shf) & 0xffff);
            int pos = start[(size_t)k * NN + n] + local;
            csr_src[pos] = src[base + i];
        }
    }
}

// h[row,j] = fp16( relu(x @ Wp + bp) ); 16 rows/block.  [R8-proven]
__global__ __launch_bounds__(256) void proj_kernel(const void* __restrict__ x,
                                                   const void* __restrict__ Wp,
                                                   const void* __restrict__ bp,
                                                   fp16* __restrict__ h,
                                                   const int* __restrict__ flag) {
    int f32 = *flag;
    __shared__ float xs[16 * IND];
    int row0 = blockIdx.x * 16;
    for (int i = threadIdx.x; i < 16 * IND; i += 256) {
        int r = i >> 6, c = i & 63;
        xs[i] = loadT(x, (size_t)(row0 + r) * IND + c, f32);
    }
    __syncthreads();
    int j = threadIdx.x & 127;
    int rr = threadIdx.x >> 7;
    float acc[8] = {0.f, 0.f, 0.f, 0.f, 0.f, 0.f, 0.f, 0.f};
    for (int k = 0; k < IND; ++k) {
        float w = loadT(Wp, (size_t)k * HD + j, f32);
#pragma unroll
        for (int r = 0; r < 8; ++r) acc[r] += xs[(rr * 8 + r) * IND + k] * w;
    }
    float b = loadT(bp, j, f32);
#pragma unroll
    for (int r = 0; r < 8; ++r) {
        int row = row0 + rr * 8 + r;
        h[(size_t)row * HD + j] = (fp16)fmaxf(acc[r] + b, 0.0f);
    }
}

// p[row,:] = norm_src[row] * (h[row,:] @ W)  via mfma_f32_16x16x32_f16. [R10-proven]
__global__ __launch_bounds__(256) void pgemm_kernel(const fp16* __restrict__ h,
                                                    const void* __restrict__ W,
                                                    int wofs,
                                                    const float* __restrict__ norm_src,
                                                    const int* __restrict__ flag,
                                                    fp16* __restrict__ p) {
    int f32 = *flag;
    __shared__ fp16 wt[128 * 136];
    int tid = threadIdx.x;
    for (int idx = tid; idx < 128 * 128; idx += 256) {
        int k = idx >> 7, n = idx & 127;
        wt[n * 136 + k] = (fp16)loadT(W, (size_t)wofs + (size_t)k * 128 + n, f32);
    }
    __syncthreads();

    int w = tid >> 6;
    int lane = tid & 63;
    int m = lane & 15;
    int q = lane >> 4;
    int row0 = blockIdx.x * 64 + w * 16;

    int rowA = row0 + m;
    if (rowA > NN - 1) rowA = NN - 1;
    const fp16* Arow = h + (size_t)rowA * 128 + q * 8;
    half8 a[4];
#pragma unroll
    for (int kk = 0; kk < 4; ++kk) a[kk] = *(const half8*)(Arow + kk * 32);

    float ns[4];
#pragma unroll
    for (int r = 0; r < 4; ++r) {
        int row = row0 + q * 4 + r;
        ns[r] = norm_src[row < NN ? row : NN - 1];
    }

#pragma unroll
    for (int t = 0; t < 8; ++t) {
        f32x4 c = {0.f, 0.f, 0.f, 0.f};
        const fp16* bt = &wt[(t * 16 + m) * 136 + q * 8];
#pragma unroll
        for (int kk = 0; kk < 4; ++kk) {
            half8 b = *(const half8*)(bt + kk * 32);
            c = __builtin_amdgcn_mfma_f32_16x16x32_f16(a[kk], b, c, 0, 0, 0);
        }
        int col = t * 16 + m;
#pragma unroll
        for (int r = 0; r < 4; ++r) {
            int row = row0 + q * 4 + r;
            if (row < NN)
                p[(size_t)row * 128 + col] = (fp16)(c[r] * ns[r]);
        }
    }
}

// out[n,:] = relu(norm_dst[n] * sum_e p[csr_src[e],:] + bias)  [R8-proven]
__global__ __launch_bounds__(256) void gather_kernel(const fp16* __restrict__ p,
                                                     const int* __restrict__ row_ofs,
                                                     const int* __restrict__ csr_src,
                                                     const float* __restrict__ norm_dst,
                                                     const void* __restrict__ bias,
                                                     int bofs,
                                                     const int* __restrict__ flag,
                                                     fp16* __restrict__ h_out,
                                                     void* __restrict__ outv,
                                                     int is_final) {
    int f32 = *flag;
    int g = threadIdx.x >> 4;
    int c = threadIdx.x & 15;
    int n = blockIdx.x * 16 + g;
    int e0 = row_ofs[n];
    int e1 = row_ofs[n + 1];
    float acc[8] = {0.f, 0.f, 0.f, 0.f, 0.f, 0.f, 0.f, 0.f};
    int e = e0;
    for (; e + 3 < e1; e += 4) {
        int s0 = csr_src[e], s1 = csr_src[e + 1];
        int s2 = csr_src[e + 2], s3 = csr_src[e + 3];
        half8 v0 = *(const half8*)(p + (size_t)s0 * HD + c * 8);
        half8 v1 = *(const half8*)(p + (size_t)s1 * HD + c * 8);
        half8 v2 = *(const half8*)(p + (size_t)s2 * HD + c * 8);
        half8 v3 = *(const half8*)(p + (size_t)s3 * HD + c * 8);
#pragma unroll
        for (int j = 0; j < 8; ++j)
            acc[j] += ((float)v0[j] + (float)v1[j]) + ((float)v2[j] + (float)v3[j]);
    }
    for (; e < e1; ++e) {
        int s0 = csr_src[e];
        half8 v0 = *(const half8*)(p + (size_t)s0 * HD + c * 8);
#pragma unroll
        for (int j = 0; j < 8; ++j) acc[j] += (float)v0[j];
    }
    float nd = norm_dst[n];
#pragma unroll
    for (int j = 0; j < 8; ++j) {
        float bv = loadT(bias, (size_t)bofs + c * 8 + j, f32);
        float v = fmaxf(acc[j] * nd + bv, 0.0f);
        size_t idx = (size_t)n * HD + c * 8 + j;
        if (is_final) {
            if (f32) ((float*)outv)[idx] = v;
            else ((bf16*)outv)[idx] = __float2bfloat16(v);
        } else {
            h_out[idx] = (fp16)v;
        }
    }
}

extern "C" void kernel_launch(void* const* d_in, const int* in_sizes, int n_in,
                              void* d_out, int out_size, void* d_ws, size_t ws_size,
                              hipStream_t stream) {
    const void* x  = d_in[0];
    const int* src = (const int*)d_in[1];
    const int* dst = (const int*)d_in[2];
    const void* Wp = d_in[3];
    const void* bp = d_in[4];
    const void* Wl = d_in[5];
    const void* bl = d_in[6];

    fp16*  h        = (fp16*)d_ws;                       // NN*HD fp16 (12.8 MB)
    fp16*  p        = h + (size_t)NN * HD;               // NN*HD fp16 (12.8 MB)
    float* norm_src = (float*)(p + (size_t)NN * HD);     // NN
    float* norm_dst = norm_src + NN;                     // NN
    int*   row_ofs  = (int*)(norm_dst + NN);             // NN+1
    int*   bsum     = row_ofs + NN + 1;                  // 256
    int*   csr_src  = bsum + 256;                        // EE (3.2 MB)
    int*   flag     = csr_src + EE;                      // 1

    // Transient aliases (lifetimes disjoint from h/p by launch order):
    // PD|PS live in p (dead until pgemm l=0); start lives in h (dead until proj).
    unsigned* PD    = (unsigned*)p;                      // KCH*NPART*PWORDS (6.4 MB)
    unsigned* PS    = PD + (size_t)KCH * NPART * PWORDS; // 6.4 MB  (PD+PS == p exactly)
    int*      start = (int*)h;                           // KCH*NN (12.8 MB == h exactly)

    size_t need = (size_t)((char*)(flag + 1) - (char*)d_ws);
    if (ws_size < need) {
        fill_sentinel<<<(out_size + 255) / 256, 256, 0, stream>>>((bf16*)d_out, out_size);
        return;
    }

    const int NB = (NN + 255) / 256;  // 196

    detect_kernel<<<1, 64, 0, stream>>>((const unsigned short*)x, flag);
    histA_kernel<<<2 * NPART * KCH, 256, 0, stream>>>(src, dst, PD, PS);
    normscanB_kernel<<<NB, 256, 0, stream>>>(PD, PS, norm_src, norm_dst, row_ofs, bsum);
    scan2_kernel<<<1, 256, 0, stream>>>(bsum, NB);
    scan3_kernel<<<NB, 256, 0, stream>>>(row_ofs, bsum, PD, start);
    placeC_kernel<<<NPART * KCH, 256, 0, stream>>>(src, dst, start, csr_src);

    // h = relu(x @ Wp + bp)   (overwrites the dead `start` alias)
    proj_kernel<<<NN / 16, 256, 0, stream>>>(x, Wp, bp, h, flag);

    for (int l = 0; l < 3; ++l) {
        // p = norm_src ⊙ (h @ Wl)   [MFMA; first write overwrites dead PD/PS]
        pgemm_kernel<<<(NN + 63) / 64, 256, 0, stream>>>(h, Wl, l * HD * HD, norm_src, flag, p);
        // h_next = relu(norm_dst ⊙ (A @ p) + bl)
        gather_kernel<<<NN / 16, 256, 0, stream>>>(
            p, row_ofs, csr_src, norm_dst, bl, l * HD, flag,
            h, d_out, (l == 2) ? 1 : 0);
    }
}

// Round 12
// 408.963 us; speedup vs baseline: 1.2708x; 1.0134x over previous
//
#include <hip/hip_runtime.h>
#include <hip/hip_bf16.h>

#define NN 50000
#define EE 800000
#define IND 64
#define HD 128

#define KCH 64            // edge chunks
#define CHUNK 12500       // EE / KCH
#define NPART 4           // node partitions
#define PART_N 12500      // NN / NPART
#define PWORDS 6250       // PART_N / 2 (16-bit packed pairs)

typedef __hip_bfloat16 bf16;
typedef _Float16 fp16;
typedef _Float16 half8 __attribute__((ext_vector_type(8)));
typedef __attribute__((ext_vector_type(4))) float f32x4;

__device__ __forceinline__ float loadT(const void* p, size_t i, int f32) {
    if (f32) return ((const float*)p)[i];
    return __bfloat162float(((const bf16*)p)[i]);
}

// flag=1 if float inputs are fp32, flag=0 if bf16.
__global__ void detect_kernel(const unsigned short* __restrict__ xraw,
                              int* __restrict__ flag) {
    if (threadIdx.x == 0) {
        int f = 0;
        for (int i = 0; i < 256; i += 2) {
            unsigned int w = ((unsigned int)xraw[i]) << 16;
            float a = fabsf(__uint_as_float(w));
            if (!(a <= 1.0e6f)) f = 1;
        }
        *flag = f;
    }
}

__global__ void fill_sentinel(bf16* __restrict__ out, int n) {
    int i = blockIdx.x * 256 + threadIdx.x;
    if (i < n) out[i] = __float2bfloat16(0.123f);
}

// Chunked LDS histograms, zero global atomics. [R11-proven]
__global__ __launch_bounds__(256) void histA_kernel(const int* __restrict__ src,
                                                    const int* __restrict__ dst,
                                                    unsigned* __restrict__ PD,
                                                    unsigned* __restrict__ PS) {
    int b = blockIdx.x;
    int stream = b >> 8;
    int part = (b >> 6) & 3;
    int k = b & 63;
    const int* ebuf = stream ? src : dst;
    unsigned* out = (stream ? PS : PD) + (size_t)(k * NPART + part) * PWORDS;
    __shared__ unsigned sh[PWORDS];
    for (int w = threadIdx.x; w < PWORDS; w += 256) sh[w] = 0;
    __syncthreads();
    int base = k * CHUNK;
    int pb = part * PART_N;
    for (int i = threadIdx.x; i < CHUNK; i += 256) {
        int n = ebuf[base + i];
        unsigned r = (unsigned)(n - pb);
        if (r < PART_N)
            atomicAdd(&sh[r >> 1], 1u << ((r & 1) * 16));
    }
    __syncthreads();
    for (int w = threadIdx.x; w < PWORDS; w += 256) out[w] = sh[w];
}

// Sum chunk partials -> degrees -> norms; block-scan deg_in. [R11-proven]
__global__ __launch_bounds__(256) void normscanB_kernel(const unsigned* __restrict__ PD,
                                                        const unsigned* __restrict__ PS,
                                                        float* __restrict__ norm_src,
                                                        float* __restrict__ norm_dst,
                                                        int* __restrict__ row_ofs,
                                                        int* __restrict__ bsum) {
    __shared__ int sm[256];
    int t = threadIdx.x;
    int i = blockIdx.x * 256 + t;
    int d = 0;
    if (i < NN) {
        int part = i / PART_N;
        unsigned r = (unsigned)(i - part * PART_N);
        int w = r >> 1, shf = (r & 1) * 16;
        int s = 0;
#pragma unroll
        for (int k = 0; k < KCH; ++k) {
            d += (PD[(size_t)(k * NPART + part) * PWORDS + w] >> shf) & 0xffff;
            s += (PS[(size_t)(k * NPART + part) * PWORDS + w] >> shf) & 0xffff;
        }
        norm_src[i] = rsqrtf((float)(s < 1 ? 1 : s));
        norm_dst[i] = rsqrtf((float)(d < 1 ? 1 : d));
    }
    sm[t] = d;
    __syncthreads();
    for (int ofs = 1; ofs < 256; ofs <<= 1) {
        int add = (t >= ofs) ? sm[t - ofs] : 0;
        __syncthreads();
        sm[t] += add;
        __syncthreads();
    }
    if (i < NN) row_ofs[i] = sm[t] - d;
    if (t == 255) bsum[blockIdx.x] = sm[255];
}

__global__ __launch_bounds__(256) void scan2_kernel(int* __restrict__ bsum, int nb) {
    __shared__ int s[256];
    int t = threadIdx.x;
    int v = (t < nb) ? bsum[t] : 0;
    s[t] = v;
    __syncthreads();
    for (int ofs = 1; ofs < 256; ofs <<= 1) {
        int add = (t >= ofs) ? s[t - ofs] : 0;
        __syncthreads();
        s[t] += add;
        __syncthreads();
    }
    if (t < nb) bsum[t] = s[t] - v;
}

// Finalize row_ofs; emit per-chunk absolute bucket cursors start[k][n]. [R11-proven]
__global__ __launch_bounds__(256) void scan3_kernel(int* __restrict__ row_ofs,
                                                    const int* __restrict__ bsum,
                                                    const unsigned* __restrict__ PD,
                                                    int* __restrict__ start) {
    int t = threadIdx.x;
    int i = blockIdx.x * 256 + t;
    if (i < NN) {
        int v = row_ofs[i] + bsum[blockIdx.x];
        row_ofs[i] = v;
        int part = i / PART_N;
        unsigned r = (unsigned)(i - part * PART_N);
        int w = r >> 1, shf = (r & 1) * 16;
        int run = v;
#pragma unroll
        for (int k = 0; k < KCH; ++k) {
            start[(size_t)k * NN + i] = run;
            run += (PD[(size_t)(k * NPART + part) * PWORDS + w] >> shf) & 0xffff;
        }
    }
    if (i == 0) row_ofs[NN] = EE;
}

// CSR placement via LDS rank; no global atomics. [R11-proven]
__global__ __launch_bounds__(256) void placeC_kernel(const int* __restrict__ src,
                                                     const int* __restrict__ dst,
                                                     const int* __restrict__ start,
                                                     int* __restrict__ csr_src) {
    int b = blockIdx.x;
    int part = b >> 6;
    int k = b & 63;
    __shared__ unsigned sh[PWORDS];
    for (int w = threadIdx.x; w < PWORDS; w += 256) sh[w] = 0;
    __syncthreads();
    int base = k * CHUNK;
    int pb = part * PART_N;
    for (int i = threadIdx.x; i < CHUNK; i += 256) {
        int n = dst[base + i];
        unsigned r = (unsigned)(n - pb);
        if (r < PART_N) {
            unsigned shf = (r & 1) * 16;
            unsigned old = atomicAdd(&sh[r >> 1], 1u << shf);
            int local = (int)((old >> shf) & 0xffff);
            int pos = start[(size_t)k * NN + n] + local;
            csr_src[pos] = src[base + i];
        }
    }
}

// *** CHANGE 1: proj via MFMA (pgemm pattern at K=64) ***
// h[row,:] = fp16(relu(x[row,:] @ Wp + bp)); 64 rows/block, 4 waves.
// x-tile and Wp^T staged fp16 in LDS (stride 72). Layouts per R10-proven pgemm.
__global__ __launch_bounds__(256) void proj_kernel(const void* __restrict__ x,
                                                   const void* __restrict__ Wp,
                                                   const void* __restrict__ bp,
                                                   fp16* __restrict__ h,
                                                   const int* __restrict__ flag) {
    int f32 = *flag;
    __shared__ fp16 wt[128 * 72];  // Wp^T: wt[n*72+k], n=0..127, k=0..63
    __shared__ fp16 xs[64 * 72];   // x-tile: xs[r*72+c]
    int tid = threadIdx.x;
    for (int idx = tid; idx < 64 * 128; idx += 256) {
        int k = idx >> 7, n = idx & 127;
        wt[n * 72 + k] = (fp16)loadT(Wp, (size_t)k * 128 + n, f32);
    }
    int row0 = blockIdx.x * 64;
    for (int idx = tid; idx < 64 * 64; idx += 256) {
        int r = idx >> 6, c = idx & 63;
        int row = row0 + r;
        if (row > NN - 1) row = NN - 1;
        xs[r * 72 + c] = (fp16)loadT(x, (size_t)row * IND + c, f32);
    }
    __syncthreads();

    int w = tid >> 6;
    int lane = tid & 63;
    int m = lane & 15;
    int q = lane >> 4;
    int rbase = w * 16;

    half8 a0 = *(const half8*)&xs[(rbase + m) * 72 + q * 8];
    half8 a1 = *(const half8*)&xs[(rbase + m) * 72 + 32 + q * 8];

#pragma unroll
    for (int t = 0; t < 8; ++t) {
        f32x4 c = {0.f, 0.f, 0.f, 0.f};
        const fp16* bt = &wt[(t * 16 + m) * 72 + q * 8];
        c = __builtin_amdgcn_mfma_f32_16x16x32_f16(a0, *(const half8*)bt, c, 0, 0, 0);
        c = __builtin_amdgcn_mfma_f32_16x16x32_f16(a1, *(const half8*)(bt + 32), c, 0, 0, 0);
        int col = t * 16 + m;
        float bv = loadT(bp, col, f32);
#pragma unroll
        for (int r = 0; r < 4; ++r) {
            int row = row0 + rbase + q * 4 + r;
            if (row < NN)
                h[(size_t)row * HD + col] = (fp16)fmaxf(c[r] + bv, 0.f);
        }
    }
}

// p[row,:] = norm_src[row] * (h[row,:] @ W)  via mfma_f32_16x16x32_f16. [R10-proven]
__global__ __launch_bounds__(256) void pgemm_kernel(const fp16* __restrict__ h,
                                                    const void* __restrict__ W,
                                                    int wofs,
                                                    const float* __restrict__ norm_src,
                                                    const int* __restrict__ flag,
                                                    fp16* __restrict__ p) {
    int f32 = *flag;
    __shared__ fp16 wt[128 * 136];
    int tid = threadIdx.x;
    for (int idx = tid; idx < 128 * 128; idx += 256) {
        int k = idx >> 7, n = idx & 127;
        wt[n * 136 + k] = (fp16)loadT(W, (size_t)wofs + (size_t)k * 128 + n, f32);
    }
    __syncthreads();

    int w = tid >> 6;
    int lane = tid & 63;
    int m = lane & 15;
    int q = lane >> 4;
    int row0 = blockIdx.x * 64 + w * 16;

    int rowA = row0 + m;
    if (rowA > NN - 1) rowA = NN - 1;
    const fp16* Arow = h + (size_t)rowA * 128 + q * 8;
    half8 a[4];
#pragma unroll
    for (int kk = 0; kk < 4; ++kk) a[kk] = *(const half8*)(Arow + kk * 32);

    float ns[4];
#pragma unroll
    for (int r = 0; r < 4; ++r) {
        int row = row0 + q * 4 + r;
        ns[r] = norm_src[row < NN ? row : NN - 1];
    }

#pragma unroll
    for (int t = 0; t < 8; ++t) {
        f32x4 c = {0.f, 0.f, 0.f, 0.f};
        const fp16* bt = &wt[(t * 16 + m) * 136 + q * 8];
#pragma unroll
        for (int kk = 0; kk < 4; ++kk) {
            half8 b = *(const half8*)(bt + kk * 32);
            c = __builtin_amdgcn_mfma_f32_16x16x32_f16(a[kk], b, c, 0, 0, 0);
        }
        int col = t * 16 + m;
#pragma unroll
        for (int r = 0; r < 4; ++r) {
            int row = row0 + q * 4 + r;
            if (row < NN)
                p[(size_t)row * 128 + col] = (fp16)(c[r] * ns[r]);
        }
    }
}

// *** CHANGE 2: gather with 8-deep edge ILP ***
// out[n,:] = relu(norm_dst[n] * sum_e p[csr_src[e],:] + bias)
__global__ __launch_bounds__(256) void gather_kernel(const fp16* __restrict__ p,
                                                     const int* __restrict__ row_ofs,
                                                     const int* __restrict__ csr_src,
                                                     const float* __restrict__ norm_dst,
                                                     const void* __restrict__ bias,
                                                     int bofs,
                                                     const int* __restrict__ flag,
                                                     fp16* __restrict__ h_out,
                                                     void* __restrict__ outv,
                                                     int is_final) {
    int f32 = *flag;
    int g = threadIdx.x >> 4;
    int c = threadIdx.x & 15;
    int n = blockIdx.x * 16 + g;
    int e0 = row_ofs[n];
    int e1 = row_ofs[n + 1];
    float acc[8] = {0.f, 0.f, 0.f, 0.f, 0.f, 0.f, 0.f, 0.f};
    int e = e0;
    for (; e + 7 < e1; e += 8) {
        int s[8];
#pragma unroll
        for (int u = 0; u < 8; ++u) s[u] = csr_src[e + u];
        half8 v[8];
#pragma unroll
        for (int u = 0; u < 8; ++u)
            v[u] = *(const half8*)(p + (size_t)s[u] * HD + c * 8);
#pragma unroll
        for (int j = 0; j < 8; ++j)
            acc[j] += (((float)v[0][j] + (float)v[1][j]) + ((float)v[2][j] + (float)v[3][j])) +
                      (((float)v[4][j] + (float)v[5][j]) + ((float)v[6][j] + (float)v[7][j]));
    }
    for (; e + 3 < e1; e += 4) {
        int s0 = csr_src[e], s1 = csr_src[e + 1];
        int s2 = csr_src[e + 2], s3 = csr_src[e + 3];
        half8 v0 = *(const half8*)(p + (size_t)s0 * HD + c * 8);
        half8 v1 = *(const half8*)(p + (size_t)s1 * HD + c * 8);
        half8 v2 = *(const half8*)(p + (size_t)s2 * HD + c * 8);
        half8 v3 = *(const half8*)(p + (size_t)s3 * HD + c * 8);
#pragma unroll
        for (int j = 0; j < 8; ++j)
            acc[j] += ((float)v0[j] + (float)v1[j]) + ((float)v2[j] + (float)v3[j]);
    }
    for (; e < e1; ++e) {
        int s0 = csr_src[e];
        half8 v0 = *(const half8*)(p + (size_t)s0 * HD + c * 8);
#pragma unroll
        for (int j = 0; j < 8; ++j) acc[j] += (float)v0[j];
    }
    float nd = norm_dst[n];
#pragma unroll
    for (int j = 0; j < 8; ++j) {
        float bv = loadT(bias, (size_t)bofs + c * 8 + j, f32);
        float v = fmaxf(acc[j] * nd + bv, 0.0f);
        size_t idx = (size_t)n * HD + c * 8 + j;
        if (is_final) {
            if (f32) ((float*)outv)[idx] = v;
            else ((bf16*)outv)[idx] = __float2bfloat16(v);
        } else {
            h_out[idx] = (fp16)v;
        }
    }
}

extern "C" void kernel_launch(void* const* d_in, const int* in_sizes, int n_in,
                              void* d_out, int out_size, void* d_ws, size_t ws_size,
                              hipStream_t stream) {
    const void* x  = d_in[0];
    const int* src = (const int*)d_in[1];
    const int* dst = (const int*)d_in[2];
    const void* Wp = d_in[3];
    const void* bp = d_in[4];
    const void* Wl = d_in[5];
    const void* bl = d_in[6];

    fp16*  h        = (fp16*)d_ws;                       // NN*HD fp16 (12.8 MB)
    fp16*  p        = h + (size_t)NN * HD;               // NN*HD fp16 (12.8 MB)
    float* norm_src = (float*)(p + (size_t)NN * HD);     // NN
    float* norm_dst = norm_src + NN;                     // NN
    int*   row_ofs  = (int*)(norm_dst + NN);             // NN+1
    int*   bsum     = row_ofs + NN + 1;                  // 256
    int*   csr_src  = bsum + 256;                        // EE (3.2 MB)
    int*   flag     = csr_src + EE;                      // 1

    // Transient aliases (lifetimes disjoint from h/p by launch order):
    unsigned* PD    = (unsigned*)p;                      // KCH*NPART*PWORDS
    unsigned* PS    = PD + (size_t)KCH * NPART * PWORDS; // (PD+PS == p exactly)
    int*      start = (int*)h;                           // KCH*NN (== h exactly)

    size_t need = (size_t)((char*)(flag + 1) - (char*)d_ws);
    if (ws_size < need) {
        fill_sentinel<<<(out_size + 255) / 256, 256, 0, stream>>>((bf16*)d_out, out_size);
        return;
    }

    const int NB = (NN + 255) / 256;  // 196
    const int MB = (NN + 63) / 64;    // 782

    detect_kernel<<<1, 64, 0, stream>>>((const unsigned short*)x, flag);
    histA_kernel<<<2 * NPART * KCH, 256, 0, stream>>>(src, dst, PD, PS);
    normscanB_kernel<<<NB, 256, 0, stream>>>(PD, PS, norm_src, norm_dst, row_ofs, bsum);
    scan2_kernel<<<1, 256, 0, stream>>>(bsum, NB);
    scan3_kernel<<<NB, 256, 0, stream>>>(row_ofs, bsum, PD, start);
    placeC_kernel<<<NPART * KCH, 256, 0, stream>>>(src, dst, start, csr_src);

    // h = relu(x @ Wp + bp)   [MFMA]
    proj_kernel<<<MB, 256, 0, stream>>>(x, Wp, bp, h, flag);

    for (int l = 0; l < 3; ++l) {
        // p = norm_src ⊙ (h @ Wl)   [MFMA]
        pgemm_kernel<<<MB, 256, 0, stream>>>(h, Wl, l * HD * HD, norm_src, flag, p);
        // h_next = relu(norm_dst ⊙ (A @ p) + bl)
        gather_kernel<<<NN / 16, 256, 0, stream>>>(
            p, row_ofs, csr_src, norm_dst, bl, l * HD, flag,
            h, d_out, (l == 2) ? 1 : 0);
    }
}

// Round 13
// 389.370 us; speedup vs baseline: 1.3348x; 1.0503x over previous
//
#include <hip/hip_runtime.h>
#include <hip/hip_bf16.h>

#define NN 50000
#define EE 800000
#define IND 64
#define HD 128

#define KCH 64            // edge chunks
#define CHUNK 12500       // EE / KCH
#define NPART 4           // node partitions
#define PART_N 12500      // NN / NPART
#define PWORDS 6250       // PART_N / 2 (16-bit packed pairs)
#define NB 196            // ceil(NN/256)

typedef __hip_bfloat16 bf16;
typedef _Float16 fp16;
typedef _Float16 half8 __attribute__((ext_vector_type(8)));
typedef short short8 __attribute__((ext_vector_type(8)));
typedef __attribute__((ext_vector_type(4))) float f32x4;

__device__ __forceinline__ float loadT(const void* p, size_t i, int f32) {
    if (f32) return ((const float*)p)[i];
    return __bfloat162float(((const bf16*)p)[i]);
}

__device__ __forceinline__ float b2f_raw(short s) {
    return __uint_as_float(((unsigned int)(unsigned short)s) << 16);
}

// flag=1 if float inputs are fp32, flag=0 if bf16.
__global__ void detect_kernel(const unsigned short* __restrict__ xraw,
                              int* __restrict__ flag) {
    if (threadIdx.x == 0) {
        int f = 0;
        for (int i = 0; i < 256; i += 2) {
            unsigned int w = ((unsigned int)xraw[i]) << 16;
            float a = fabsf(__uint_as_float(w));
            if (!(a <= 1.0e6f)) f = 1;
        }
        *flag = f;
    }
}

__global__ void fill_sentinel(bf16* __restrict__ out, int n) {
    int i = blockIdx.x * 256 + threadIdx.x;
    if (i < n) out[i] = __float2bfloat16(0.123f);
}

// One-time weight convert+transpose to fp16: WpT[col][k] (128x64) then
// WlT[l][col][k] (3 x 128x128). Total 57344 fp16 = 114KB, L2-resident after.
__global__ __launch_bounds__(256) void wconv_kernel(const void* __restrict__ Wp,
                                                    const void* __restrict__ Wl,
                                                    const int* __restrict__ flag,
                                                    fp16* __restrict__ wbuf) {
    int f32 = *flag;
    int i = blockIdx.x * 256 + threadIdx.x;
    if (i < 8192) {
        int col = i >> 6, k = i & 63;
        wbuf[col * 64 + k] = (fp16)loadT(Wp, (size_t)k * 128 + col, f32);
    } else if (i < 57344) {
        int j = i - 8192;
        int l = j >> 14;
        int r = j & 16383;
        int col = r >> 7, k = r & 127;
        wbuf[8192 + l * 16384 + col * 128 + k] =
            (fp16)loadT(Wl, (size_t)l * 16384 + (size_t)k * 128 + col, f32);
    }
}

// Chunked LDS histograms, zero global atomics. [R11-proven]
__global__ __launch_bounds__(256) void histA_kernel(const int* __restrict__ src,
                                                    const int* __restrict__ dst,
                                                    unsigned* __restrict__ PD,
                                                    unsigned* __restrict__ PS) {
    int b = blockIdx.x;
    int stream = b >> 8;
    int part = (b >> 6) & 3;
    int k = b & 63;
    const int* ebuf = stream ? src : dst;
    unsigned* out = (stream ? PS : PD) + (size_t)(k * NPART + part) * PWORDS;
    __shared__ unsigned sh[PWORDS];
    for (int w = threadIdx.x; w < PWORDS; w += 256) sh[w] = 0;
    __syncthreads();
    int base = k * CHUNK;
    int pb = part * PART_N;
    for (int i = threadIdx.x; i < CHUNK; i += 256) {
        int n = ebuf[base + i];
        unsigned r = (unsigned)(n - pb);
        if (r < PART_N)
            atomicAdd(&sh[r >> 1], 1u << ((r & 1) * 16));
    }
    __syncthreads();
    for (int w = threadIdx.x; w < PWORDS; w += 256) out[w] = sh[w];
}

// Sum chunk partials -> degrees -> norms; block-scan deg_in; raw block totals to bsum.
__global__ __launch_bounds__(256) void normscanB_kernel(const unsigned* __restrict__ PD,
                                                        const unsigned* __restrict__ PS,
                                                        float* __restrict__ norm_src,
                                                        float* __restrict__ norm_dst,
                                                        int* __restrict__ row_ofs,
                                                        int* __restrict__ bsum) {
    __shared__ int sm[256];
    int t = threadIdx.x;
    int i = blockIdx.x * 256 + t;
    int d = 0;
    if (i < NN) {
        int part = i / PART_N;
        unsigned r = (unsigned)(i - part * PART_N);
        int w = r >> 1, shf = (r & 1) * 16;
        int s = 0;
#pragma unroll
        for (int k = 0; k < KCH; ++k) {
            d += (PD[(size_t)(k * NPART + part) * PWORDS + w] >> shf) & 0xffff;
            s += (PS[(size_t)(k * NPART + part) * PWORDS + w] >> shf) & 0xffff;
        }
        norm_src[i] = rsqrtf((float)(s < 1 ? 1 : s));
        norm_dst[i] = rsqrtf((float)(d < 1 ? 1 : d));
    }
    sm[t] = d;
    __syncthreads();
    for (int ofs = 1; ofs < 256; ofs <<= 1) {
        int add = (t >= ofs) ? sm[t - ofs] : 0;
        __syncthreads();
        sm[t] += add;
        __syncthreads();
    }
    if (i < NN) row_ofs[i] = sm[t] - d;
    if (t == 255) bsum[blockIdx.x] = sm[255];
}

// Finalize row_ofs (self-computed block prefix over bsum — scan2 eliminated);
// emit per-chunk absolute bucket cursors start[k][n].
__global__ __launch_bounds__(256) void scan3_kernel(int* __restrict__ row_ofs,
                                                    const int* __restrict__ bsum,
                                                    const unsigned* __restrict__ PD,
                                                    int* __restrict__ start) {
    __shared__ int sp[256];
    int t = threadIdx.x;
    sp[t] = (t < NB && t < (int)blockIdx.x) ? bsum[t] : 0;
    __syncthreads();
    for (int o = 128; o > 0; o >>= 1) {
        if (t < o) sp[t] += sp[t + o];
        __syncthreads();
    }
    int pref = sp[0];
    int i = blockIdx.x * 256 + t;
    if (i < NN) {
        int v = row_ofs[i] + pref;
        row_ofs[i] = v;
        int part = i / PART_N;
        unsigned r = (unsigned)(i - part * PART_N);
        int w = r >> 1, shf = (r & 1) * 16;
        int run = v;
#pragma unroll
        for (int k = 0; k < KCH; ++k) {
            start[(size_t)k * NN + i] = run;
            run += (PD[(size_t)(k * NPART + part) * PWORDS + w] >> shf) & 0xffff;
        }
    }
    if (i == 0) row_ofs[NN] = EE;
}

// CSR placement via LDS rank; no global atomics. [R11-proven]
__global__ __launch_bounds__(256) void placeC_kernel(const int* __restrict__ src,
                                                     const int* __restrict__ dst,
                                                     const int* __restrict__ start,
                                                     int* __restrict__ csr_src) {
    int b = blockIdx.x;
    int part = b >> 6;
    int k = b & 63;
    __shared__ unsigned sh[PWORDS];
    for (int w = threadIdx.x; w < PWORDS; w += 256) sh[w] = 0;
    __syncthreads();
    int base = k * CHUNK;
    int pb = part * PART_N;
    for (int i = threadIdx.x; i < CHUNK; i += 256) {
        int n = dst[base + i];
        unsigned r = (unsigned)(n - pb);
        if (r < PART_N) {
            unsigned shf = (r & 1) * 16;
            unsigned old = atomicAdd(&sh[r >> 1], 1u << shf);
            int local = (int)((old >> shf) & 0xffff);
            int pos = start[(size_t)k * NN + n] + local;
            csr_src[pos] = src[base + i];
        }
    }
}

// LDS-free MFMA proj: h = fp16(relu(x @ Wp + bp)). 64 rows/block, 4 waves.
// B-frags direct from WpT fp16 global (identical element mapping to the
// R10-proven LDS path: lane(m,q), col=t*16+m needs WpT[col][kk*32+q*8 ..+7]).
__global__ __launch_bounds__(256) void proj_kernel(const void* __restrict__ x,
                                                   const fp16* __restrict__ wpT,
                                                   const void* __restrict__ bp,
                                                   const int* __restrict__ flag,
                                                   fp16* __restrict__ h) {
    int f32 = *flag;
    int tid = threadIdx.x;
    int w = tid >> 6;
    int lane = tid & 63;
    int m = lane & 15;
    int q = lane >> 4;
    int row0 = blockIdx.x * 64 + w * 16;

    int rowA = row0 + m;
    if (rowA > NN - 1) rowA = NN - 1;
    half8 a0, a1;
    if (!f32) {
        short8 r0 = *(const short8*)((const short*)x + (size_t)rowA * IND + q * 8);
        short8 r1 = *(const short8*)((const short*)x + (size_t)rowA * IND + 32 + q * 8);
#pragma unroll
        for (int j = 0; j < 8; ++j) {
            a0[j] = (fp16)b2f_raw(r0[j]);
            a1[j] = (fp16)b2f_raw(r1[j]);
        }
    } else {
#pragma unroll
        for (int j = 0; j < 8; ++j) {
            a0[j] = (fp16)((const float*)x)[(size_t)rowA * IND + q * 8 + j];
            a1[j] = (fp16)((const float*)x)[(size_t)rowA * IND + 32 + q * 8 + j];
        }
    }

#pragma unroll
    for (int t = 0; t < 8; ++t) {
        int col = t * 16 + m;
        const fp16* bt = wpT + (size_t)col * 64 + q * 8;
        f32x4 c = {0.f, 0.f, 0.f, 0.f};
        c = __builtin_amdgcn_mfma_f32_16x16x32_f16(a0, *(const half8*)bt, c, 0, 0, 0);
        c = __builtin_amdgcn_mfma_f32_16x16x32_f16(a1, *(const half8*)(bt + 32), c, 0, 0, 0);
        float bv = loadT(bp, col, f32);
#pragma unroll
        for (int r = 0; r < 4; ++r) {
            int row = row0 + q * 4 + r;
            if (row < NN)
                h[(size_t)row * HD + col] = (fp16)fmaxf(c[r] + bv, 0.f);
        }
    }
}

// LDS-free MFMA pgemm: p[row,:] = norm_src[row] * (h[row,:] @ Wl).
__global__ __launch_bounds__(256) void pgemm_kernel(const fp16* __restrict__ h,
                                                    const fp16* __restrict__ wT,
                                                    const float* __restrict__ norm_src,
                                                    fp16* __restrict__ p) {
    int tid = threadIdx.x;
    int w = tid >> 6;
    int lane = tid & 63;
    int m = lane & 15;
    int q = lane >> 4;
    int row0 = blockIdx.x * 64 + w * 16;

    int rowA = row0 + m;
    if (rowA > NN - 1) rowA = NN - 1;
    const fp16* Arow = h + (size_t)rowA * 128 + q * 8;
    half8 a[4];
#pragma unroll
    for (int kk = 0; kk < 4; ++kk) a[kk] = *(const half8*)(Arow + kk * 32);

    float ns[4];
#pragma unroll
    for (int r = 0; r < 4; ++r) {
        int row = row0 + q * 4 + r;
        ns[r] = norm_src[row < NN ? row : NN - 1];
    }

#pragma unroll
    for (int t = 0; t < 8; ++t) {
        int col = t * 16 + m;
        const fp16* bt = wT + (size_t)col * 128 + q * 8;
        f32x4 c = {0.f, 0.f, 0.f, 0.f};
#pragma unroll
        for (int kk = 0; kk < 4; ++kk) {
            half8 b = *(const half8*)(bt + kk * 32);
            c = __builtin_amdgcn_mfma_f32_16x16x32_f16(a[kk], b, c, 0, 0, 0);
        }
#pragma unroll
        for (int r = 0; r < 4; ++r) {
            int row = row0 + q * 4 + r;
            if (row < NN)
                p[(size_t)row * 128 + col] = (fp16)(c[r] * ns[r]);
        }
    }
}

// out[n,:] = relu(norm_dst[n] * sum_e p[csr_src[e],:] + bias)  [R12 unchanged]
__global__ __launch_bounds__(256) void gather_kernel(const fp16* __restrict__ p,
                                                     const int* __restrict__ row_ofs,
                                                     const int* __restrict__ csr_src,
                                                     const float* __restrict__ norm_dst,
                                                     const void* __restrict__ bias,
                                                     int bofs,
                                                     const int* __restrict__ flag,
                                                     fp16* __restrict__ h_out,
                                                     void* __restrict__ outv,
                                                     int is_final) {
    int f32 = *flag;
    int g = threadIdx.x >> 4;
    int c = threadIdx.x & 15;
    int n = blockIdx.x * 16 + g;
    int e0 = row_ofs[n];
    int e1 = row_ofs[n + 1];
    float acc[8] = {0.f, 0.f, 0.f, 0.f, 0.f, 0.f, 0.f, 0.f};
    int e = e0;
    for (; e + 7 < e1; e += 8) {
        int s[8];
#pragma unroll
        for (int u = 0; u < 8; ++u) s[u] = csr_src[e + u];
        half8 v[8];
#pragma unroll
        for (int u = 0; u < 8; ++u)
            v[u] = *(const half8*)(p + (size_t)s[u] * HD + c * 8);
#pragma unroll
        for (int j = 0; j < 8; ++j)
            acc[j] += (((float)v[0][j] + (float)v[1][j]) + ((float)v[2][j] + (float)v[3][j])) +
                      (((float)v[4][j] + (float)v[5][j]) + ((float)v[6][j] + (float)v[7][j]));
    }
    for (; e + 3 < e1; e += 4) {
        int s0 = csr_src[e], s1 = csr_src[e + 1];
        int s2 = csr_src[e + 2], s3 = csr_src[e + 3];
        half8 v0 = *(const half8*)(p + (size_t)s0 * HD + c * 8);
        half8 v1 = *(const half8*)(p + (size_t)s1 * HD + c * 8);
        half8 v2 = *(const half8*)(p + (size_t)s2 * HD + c * 8);
        half8 v3 = *(const half8*)(p + (size_t)s3 * HD + c * 8);
#pragma unroll
        for (int j = 0; j < 8; ++j)
            acc[j] += ((float)v0[j] + (float)v1[j]) + ((float)v2[j] + (float)v3[j]);
    }
    for (; e < e1; ++e) {
        int s0 = csr_src[e];
        half8 v0 = *(const half8*)(p + (size_t)s0 * HD + c * 8);
#pragma unroll
        for (int j = 0; j < 8; ++j) acc[j] += (float)v0[j];
    }
    float nd = norm_dst[n];
#pragma unroll
    for (int j = 0; j < 8; ++j) {
        float bv = loadT(bias, (size_t)bofs + c * 8 + j, f32);
        float v = fmaxf(acc[j] * nd + bv, 0.0f);
        size_t idx = (size_t)n * HD + c * 8 + j;
        if (is_final) {
            if (f32) ((float*)outv)[idx] = v;
            else ((bf16*)outv)[idx] = __float2bfloat16(v);
        } else {
            h_out[idx] = (fp16)v;
        }
    }
}

extern "C" void kernel_launch(void* const* d_in, const int* in_sizes, int n_in,
                              void* d_out, int out_size, void* d_ws, size_t ws_size,
                              hipStream_t stream) {
    const void* x  = d_in[0];
    const int* src = (const int*)d_in[1];
    const int* dst = (const int*)d_in[2];
    const void* Wp = d_in[3];
    const void* bp = d_in[4];
    const void* Wl = d_in[5];
    const void* bl = d_in[6];

    fp16*  h        = (fp16*)d_ws;                       // NN*HD fp16 (12.8 MB)
    fp16*  p        = h + (size_t)NN * HD;               // NN*HD fp16 (12.8 MB)
    float* norm_src = (float*)(p + (size_t)NN * HD);     // NN
    float* norm_dst = norm_src + NN;                     // NN
    int*   row_ofs  = (int*)(norm_dst + NN);             // NN+1
    int*   bsum     = row_ofs + NN + 1;                  // 256
    int*   csr_src  = bsum + 256;                        // EE (3.2 MB)
    int*   flag     = csr_src + EE;                      // 1
    fp16*  wbuf     = (fp16*)(flag + 1);                 // 57344 fp16 (114 KB)
    fp16*  wpT      = wbuf;                              // 128x64
    fp16*  wlT      = wbuf + 8192;                       // 3 x 128x128

    // Transient aliases (lifetimes disjoint from h/p by launch order):
    unsigned* PD    = (unsigned*)p;                      // KCH*NPART*PWORDS
    unsigned* PS    = PD + (size_t)KCH * NPART * PWORDS; // (PD+PS == p exactly)
    int*      start = (int*)h;                           // KCH*NN (== h exactly)

    size_t need = (size_t)((char*)(wbuf + 57344) - (char*)d_ws);
    if (ws_size < need) {
        fill_sentinel<<<(out_size + 255) / 256, 256, 0, stream>>>((bf16*)d_out, out_size);
        return;
    }

    const int MB = (NN + 63) / 64;    // 782

    detect_kernel<<<1, 64, 0, stream>>>((const unsigned short*)x, flag);
    wconv_kernel<<<224, 256, 0, stream>>>(Wp, Wl, flag, wbuf);
    histA_kernel<<<2 * NPART * KCH, 256, 0, stream>>>(src, dst, PD, PS);
    normscanB_kernel<<<NB, 256, 0, stream>>>(PD, PS, norm_src, norm_dst, row_ofs, bsum);
    scan3_kernel<<<NB, 256, 0, stream>>>(row_ofs, bsum, PD, start);
    placeC_kernel<<<NPART * KCH, 256, 0, stream>>>(src, dst, start, csr_src);

    // h = relu(x @ Wp + bp)   [MFMA, LDS-free]
    proj_kernel<<<MB, 256, 0, stream>>>(x, wpT, bp, flag, h);

    for (int l = 0; l < 3; ++l) {
        // p = norm_src ⊙ (h @ Wl)   [MFMA, LDS-free]
        pgemm_kernel<<<MB, 256, 0, stream>>>(h, wlT + (size_t)l * 16384, norm_src, p);
        // h_next = relu(norm_dst ⊙ (A @ p) + bl)
        gather_kernel<<<NN / 16, 256, 0, stream>>>(
            p, row_ofs, csr_src, norm_dst, bl, l * HD, flag,
            h, d_out, (l == 2) ? 1 : 0);
    }
}